// Round 9
// baseline (62.140 us; speedup 1.0000x reference)
//
#include <hip/hip_runtime.h>
#include <hip/hip_bf16.h>

// out[b,v] = dot(OT[b, pid[v], :], W[v, :]) + bias[v]
// B=32, Q=180, H=768, V=19004. fp32 in/out, bf16 MFMA inside.
#define BB 32
#define QQ 180
#define HH 768
#define VV 19004
#define VB 64
#define KQ 192       // K per quarter
#define SB 19008     // res stride (pos dim)
#define MAXDESC 480
#define ST 200       // OT LDS row stride in bf16 elems (192 + 8 pad = 400 B)

// ws layout (bytes)
#define WS_NTOT   2048     // 1 int
#define WS_SORTED 4096     // VV ints
#define WS_POSOF  81920    // VV ints
#define WS_DESC   159744   // 480 int4
#define WS_RES    167936   // 4 * 32 * 19008 * 4 = 9,732,096 B

typedef __attribute__((ext_vector_type(8))) short short8v;  // 8 bf16 (4 VGPR)
typedef __attribute__((ext_vector_type(4))) float f32x4;

__device__ __forceinline__ int cvt_pk_bf16(float lo, float hi) {  // 2 bf16 in 1 dword
    int r;
    asm("v_cvt_pk_bf16_f32 %0, %1, %2" : "=v"(r) : "v"(lo), "v"(hi));
    return r;
}

// ---------- fused pre-pass: 4-way histogram + scan + desc + scatter ----------
__global__ void prep_k(const int* __restrict__ pid, int* __restrict__ sorted,
                       int* __restrict__ posOf, int4* __restrict__ desc,
                       int* __restrict__ ntot) {
    __shared__ int cnt4[4][256];
    __shared__ int cur4[4][256];
    __shared__ int sc[256];
    __shared__ int sn[256];
    const int t = threadIdx.x;  // 1024 threads
    const int g = t & 3;
    ((int*)cnt4)[t] = 0;
    __syncthreads();
    for (int v = t; v < VV; v += 1024) atomicAdd(&cnt4[g][pid[v]], 1);
    __syncthreads();
    int c0 = 0, c1 = 0, c2 = 0, c = 0;
    if (t < 256) {
        c0 = cnt4[0][t]; c1 = cnt4[1][t]; c2 = cnt4[2][t];
        c = c0 + c1 + c2 + cnt4[3][t];
        sc[t] = c;
        sn[t] = (c + VB - 1) / VB;
    }
    __syncthreads();
    for (int off = 1; off < 256; off <<= 1) {
        int a1 = (t < 256 && t >= off) ? sc[t - off] : 0;
        int a2 = (t < 256 && t >= off) ? sn[t - off] : 0;
        __syncthreads();
        if (t < 256) { sc[t] += a1; sn[t] += a2; }
        __syncthreads();
    }
    if (t < 256) {
        const int base = sc[t] - c;      // q start in pos space
        cur4[0][t] = base;
        cur4[1][t] = base + c0;
        cur4[2][t] = base + c0 + c1;
        cur4[3][t] = base + c0 + c1 + c2;
    }
    if (t < QQ) {
        const int nch = (c + VB - 1) / VB;
        const int cb = sn[t] - nch;
        const int base = sc[t] - c;
        for (int j = 0; j < nch; ++j)
            desc[cb + j] = make_int4(t, base + j * VB, min(VB, c - j * VB), 0);
    }
    if (t == 255) *ntot = sn[255];
    __syncthreads();
    for (int v = t; v < VV; v += 1024) {
        const int q = pid[v];
        const int pos = atomicAdd(&cur4[g][q], 1);
        sorted[pos] = v;
        posOf[v] = pos;
    }
}

// ---------- main: MFMA 16x16x32 bf16, block = (chunk, K-quarter) ----------
// A = OT (M=b), B = W (N=v). 4 waves; wave w owns v-tile w (16 v's), both
// b-tiles, K=192 (6 steps x2 MFMA). OT quarter staged in LDS as bf16 (12.8 KB)
// via v_cvt_pk; W burst-loaded (12 outstanding float4/lane). Full-line
// pos-space stores. 1496 active blocks (~5.8/CU) for latency hiding.
__launch_bounds__(256)
__global__ void main_k(const float* __restrict__ OT, const float* __restrict__ W,
                       const int* __restrict__ sorted, const int4* __restrict__ desc,
                       const int* __restrict__ ntot, float* __restrict__ res) {
    const int nt = *ntot;
    const int bid = blockIdx.x;
    const int ci = bid >> 2;
    if (ci >= nt) return;
    const int kh = bid & 3;
    const int4 d = desc[ci];
    const int q     = __builtin_amdgcn_readfirstlane(d.x);
    const int start = __builtin_amdgcn_readfirstlane(d.y);
    const int len   = __builtin_amdgcn_readfirstlane(d.z);
    const int tid = threadIdx.x;

    __shared__ short OTlds[BB * ST];  // 12,800 B

    // stage OT[0..31][q][kh*192 .. +192) as bf16 (coalesced fp32 reads)
    {
        const int r = tid >> 3;   // b row 0..31
        const int o = tid & 7;    // octet
        const float* src = OT + ((size_t)r * QQ + q) * HH + kh * KQ + o * 8;
#pragma unroll
        for (int it = 0; it < 3; ++it) {
            const float4 f0 = *(const float4*)(src + it * 64);
            const float4 f1 = *(const float4*)(src + it * 64 + 4);
            int4 p;
            p.x = cvt_pk_bf16(f0.x, f0.y);
            p.y = cvt_pk_bf16(f0.z, f0.w);
            p.z = cvt_pk_bf16(f1.x, f1.y);
            p.w = cvt_pk_bf16(f1.z, f1.w);
            *(int4*)&OTlds[r * ST + it * 64 + o * 8] = p;
        }
    }

    const int lane = tid & 63;
    const int w = tid >> 6;           // v-tile
    const int co = lane & 15;         // frag col
    const int kq = lane >> 4;         // k-quad
    const int vl = 16 * w + co;       // v-local in chunk
    const int vg = sorted[start + min(vl, len - 1)];
    const float4* wp4 = (const float4*)(W + (size_t)vg * HH + kh * KQ + kq * 8);

    // burst: issue ALL W loads before any use (12 outstanding 16B/lane)
    float4 wf[12];
#pragma unroll
    for (int kk = 0; kk < 6; ++kk) {
        wf[2 * kk]     = wp4[kk * 8];
        wf[2 * kk + 1] = wp4[kk * 8 + 1];
    }

    const short* a0 = &OTlds[co * ST + kq * 8];

    __syncthreads();

    f32x4 acc0 = {0.f, 0.f, 0.f, 0.f};
    f32x4 acc1 = {0.f, 0.f, 0.f, 0.f};
#pragma unroll
    for (int kk = 0; kk < 6; ++kk) {
        const float4 wf0 = wf[2 * kk];
        const float4 wf1 = wf[2 * kk + 1];
        int4 p;
        p.x = cvt_pk_bf16(wf0.x, wf0.y);
        p.y = cvt_pk_bf16(wf0.z, wf0.w);
        p.z = cvt_pk_bf16(wf1.x, wf1.y);
        p.w = cvt_pk_bf16(wf1.z, wf1.w);
        const short8v bf = __builtin_bit_cast(short8v, p);
        const short8v a0v = *(const short8v*)(a0 + kk * 32);
        const short8v a1v = *(const short8v*)(a0 + 16 * ST + kk * 32);
        acc0 = __builtin_amdgcn_mfma_f32_16x16x32_bf16(a0v, bf, acc0, 0, 0, 0);
        acc1 = __builtin_amdgcn_mfma_f32_16x16x32_bf16(a1v, bf, acc1, 0, 0, 0);
    }

    // C[row=b][col=v]: row = (lane>>4)*4 + reg, col = lane&15  (m89-verified)
    if (vl < len) {
        float* rp = res + (size_t)(kh * BB) * SB + start + vl;
#pragma unroll
        for (int r2 = 0; r2 < 4; ++r2) {
            rp[(size_t)(kq * 4 + r2) * SB]      = acc0[r2];
            rp[(size_t)(16 + kq * 4 + r2) * SB] = acc1[r2];
        }
    }
}

// ---------- combine: gather 4 K-planes via posOf, coalesced out writes ----------
__global__ void combine_k(const float* __restrict__ res, const int* __restrict__ posOf,
                          const float* __restrict__ bias, float* __restrict__ out) {
    const int v = blockIdx.x * 256 + threadIdx.x;
    if (v >= VV) return;
    const int b = blockIdx.y;
    const int pos = posOf[v];
    const float s = res[(size_t)b * SB + pos]
                  + res[(size_t)(BB + b) * SB + pos]
                  + res[(size_t)(2 * BB + b) * SB + pos]
                  + res[(size_t)(3 * BB + b) * SB + pos];
    out[(size_t)b * VV + v] = s + bias[v];
}

extern "C" void kernel_launch(void* const* d_in, const int* in_sizes, int n_in,
                              void* d_out, int out_size, void* d_ws, size_t ws_size,
                              hipStream_t stream) {
    const float* OT   = (const float*)d_in[0];  // [B,Q,H]
    const float* W    = (const float*)d_in[1];  // [V,H]
    const float* bias = (const float*)d_in[2];  // [V]
    const int*   pid  = (const int*)d_in[3];    // [V]
    float* out = (float*)d_out;                 // [B,V]

    char* ws = (char*)d_ws;
    int*   ntot   = (int*)(ws + WS_NTOT);
    int*   sorted = (int*)(ws + WS_SORTED);
    int*   posOf  = (int*)(ws + WS_POSOF);
    int4*  desc   = (int4*)(ws + WS_DESC);
    float* res    = (float*)(ws + WS_RES);

    prep_k<<<1, 1024, 0, stream>>>(pid, sorted, posOf, desc, ntot);

    main_k<<<4 * MAXDESC, 256, 0, stream>>>(OT, W, sorted, desc, ntot, res);

    combine_k<<<dim3((VV + 255) / 256, BB), 256, 0, stream>>>(res, posOf, bias, out);
}

// Round 10
// 60.753 us; speedup vs baseline: 1.0228x; 1.0228x over previous
//
#include <hip/hip_runtime.h>
#include <hip/hip_bf16.h>

// out[b,v] = dot(OT[b, pid[v], :], W[v, :]) + bias[v]
// B=32, Q=180, H=768, V=19004. fp32 in/out, bf16 MFMA inside.
#define BB 32
#define QQ 180
#define HH 768
#define VV 19004
#define KQ 192       // K per quarter (K-split x4)
#define SB 19008     // res stride (pos dim)
#define ST 200       // OT LDS row stride in bf16 elems (192 + 8 pad)

// ws layout (bytes)
#define WS_CNT    0        // 256 ints (qcnt)
#define WS_QS     1024     // 256 ints (qstart)
#define WS_CURS   2048     // 256 ints (scatter cursor)
#define WS_SORTED 4096     // VV ints
#define WS_POSOF  81920    // VV ints
#define WS_RES    159744   // 4 * 32 * 19008 * 4 = 9,732,096 B

typedef __attribute__((ext_vector_type(8))) short short8v;  // 8 bf16 (4 VGPR)
typedef __attribute__((ext_vector_type(4))) float f32x4;

__device__ __forceinline__ short f2bf(float f) {  // RNE fp32->bf16
    unsigned u = __builtin_bit_cast(unsigned, f);
    u += 0x7FFFu + ((u >> 16) & 1u);
    return (short)(u >> 16);
}

// ---------- pre-pass (parallel, 3 small kernels) ----------
__global__ void count_k(const int* __restrict__ pid, int* __restrict__ cnt) {
    __shared__ int lc[QQ];
    for (int i = threadIdx.x; i < QQ; i += blockDim.x) lc[i] = 0;
    __syncthreads();
    for (int v = blockIdx.x * blockDim.x + threadIdx.x; v < VV;
         v += gridDim.x * blockDim.x)
        atomicAdd(&lc[pid[v]], 1);
    __syncthreads();
    for (int i = threadIdx.x; i < QQ; i += blockDim.x) {
        int c = lc[i];
        if (c) atomicAdd(&cnt[i], c);
    }
}

__global__ void scan_k(const int* __restrict__ cnt, int* __restrict__ qs,
                       int* __restrict__ cursor) {
    __shared__ int sc[256];
    const int t = threadIdx.x;
    const int c = (t < QQ) ? cnt[t] : 0;
    sc[t] = c;
    __syncthreads();
    for (int off = 1; off < 256; off <<= 1) {
        int add = (t >= off) ? sc[t - off] : 0;
        __syncthreads();
        sc[t] += add;
        __syncthreads();
    }
    const int start = sc[t] - c;   // exclusive prefix
    if (t < 256) { qs[t] = start; cursor[t] = start; }
}

__global__ void scatter_k(const int* __restrict__ pid, int* __restrict__ cursor,
                          int* __restrict__ sorted, int* __restrict__ posOf) {
    for (int v = blockIdx.x * blockDim.x + threadIdx.x; v < VV;
         v += gridDim.x * blockDim.x) {
        const int q = pid[v];
        const int pos = atomicAdd(&cursor[q], 1);
        sorted[pos] = v;
        posOf[v] = pos;
    }
}

// ---------- main: MFMA 16x16x32 bf16, block = (q, K-quarter) ----------
// grid = 180*4. q = bid>>2, kh = bid&3. 4 waves; wave w handles v-batches
// j = w, w+4, ... (16 v each), both b-halves. OT quarter staged once in LDS
// as bf16 (12.8 KB), then hoisted into 12 short8v REGISTERS per lane (no LDS
// reads in the batch loop). Per batch: 12-float4 burst of W rows, 6 K-steps
// x 2 MFMA, full-line pos-space stores. ~720 blocks = 2.8/CU.
__launch_bounds__(256)
__global__ void main_k(const float* __restrict__ OT, const float* __restrict__ W,
                       const int* __restrict__ sorted, const int* __restrict__ qs,
                       const int* __restrict__ qcnt, float* __restrict__ res) {
    const int bid = blockIdx.x;
    const int q  = bid >> 2;
    const int kh = bid & 3;
    const int start = __builtin_amdgcn_readfirstlane(qs[q]);
    const int len   = __builtin_amdgcn_readfirstlane(qcnt[q]);
    const int tid = threadIdx.x;

    __shared__ short OTlds[BB * ST];  // 12,800 B

    // stage OT[0..31][q][kh*192 .. +192) as bf16 (coalesced fp32 reads)
    {
        const int r = tid >> 3;   // b row 0..31
        const int o = tid & 7;    // octet
        const float* src = OT + ((size_t)r * QQ + q) * HH + kh * KQ + o * 8;
        short* dst = &OTlds[r * ST + o * 8];
#pragma unroll
        for (int it = 0; it < 3; ++it) {
            const float4 f0 = *(const float4*)(src + it * 64);
            const float4 f1 = *(const float4*)(src + it * 64 + 4);
            short8v s;
            s[0] = f2bf(f0.x); s[1] = f2bf(f0.y); s[2] = f2bf(f0.z); s[3] = f2bf(f0.w);
            s[4] = f2bf(f1.x); s[5] = f2bf(f1.y); s[6] = f2bf(f1.z); s[7] = f2bf(f1.w);
            *(short8v*)(dst + it * 64) = s;
        }
    }

    const int lane = tid & 63;
    const int w = tid >> 6;           // wave id: batch stride 4
    const int co = lane & 15;         // frag col (v)
    const int kq = lane >> 4;         // k-quad
    const int nb = (len + 15) >> 4;   // 16-v batches

    __syncthreads();

    // hoist this lane's OT fragments into registers (only LDS reads at all)
    short8v ot0[6], ot1[6];
#pragma unroll
    for (int kk = 0; kk < 6; ++kk) {
        ot0[kk] = *(const short8v*)&OTlds[co * ST + kq * 8 + kk * 32];
        ot1[kk] = *(const short8v*)&OTlds[(16 + co) * ST + kq * 8 + kk * 32];
    }

    for (int j = w; j < nb; j += 4) {
        const int pl = j * 16 + co;                       // pos-local
        const int pp = start + min(pl, len - 1);
        const int vg = sorted[pp];
        const float4* wp4 = (const float4*)(W + (size_t)vg * HH + kh * KQ + kq * 8);

        float4 wf[12];
#pragma unroll
        for (int kk = 0; kk < 6; ++kk) {                  // burst: 12 outstanding
            wf[2 * kk]     = wp4[kk * 8];
            wf[2 * kk + 1] = wp4[kk * 8 + 1];
        }

        f32x4 acc0 = {0.f, 0.f, 0.f, 0.f};
        f32x4 acc1 = {0.f, 0.f, 0.f, 0.f};
#pragma unroll
        for (int kk = 0; kk < 6; ++kk) {
            const float4 wf0 = wf[2 * kk];
            const float4 wf1 = wf[2 * kk + 1];
            short8v bf;
            bf[0] = f2bf(wf0.x); bf[1] = f2bf(wf0.y); bf[2] = f2bf(wf0.z); bf[3] = f2bf(wf0.w);
            bf[4] = f2bf(wf1.x); bf[5] = f2bf(wf1.y); bf[6] = f2bf(wf1.z); bf[7] = f2bf(wf1.w);
            acc0 = __builtin_amdgcn_mfma_f32_16x16x32_bf16(ot0[kk], bf, acc0, 0, 0, 0);
            acc1 = __builtin_amdgcn_mfma_f32_16x16x32_bf16(ot1[kk], bf, acc1, 0, 0, 0);
        }

        // C[row=b][col=v]: row = (lane>>4)*4 + reg, col = lane&15 (m89-verified)
        if (pl < len) {
            float* rp = res + (size_t)(kh * BB) * SB + start + pl;
#pragma unroll
            for (int r2 = 0; r2 < 4; ++r2) {
                rp[(size_t)(kq * 4 + r2) * SB]      = acc0[r2];
                rp[(size_t)(16 + kq * 4 + r2) * SB] = acc1[r2];
            }
        }
    }
}

// ---------- combine: gather 4 K-planes via posOf, coalesced out writes ----------
__global__ void combine_k(const float* __restrict__ res, const int* __restrict__ posOf,
                          const float* __restrict__ bias, float* __restrict__ out) {
    const int v = blockIdx.x * 256 + threadIdx.x;
    if (v >= VV) return;
    const int b = blockIdx.y;
    const int pos = posOf[v];
    const float s = res[(size_t)b * SB + pos]
                  + res[(size_t)(BB + b) * SB + pos]
                  + res[(size_t)(2 * BB + b) * SB + pos]
                  + res[(size_t)(3 * BB + b) * SB + pos];
    out[(size_t)b * VV + v] = s + bias[v];
}

extern "C" void kernel_launch(void* const* d_in, const int* in_sizes, int n_in,
                              void* d_out, int out_size, void* d_ws, size_t ws_size,
                              hipStream_t stream) {
    const float* OT   = (const float*)d_in[0];  // [B,Q,H]
    const float* W    = (const float*)d_in[1];  // [V,H]
    const float* bias = (const float*)d_in[2];  // [V]
    const int*   pid  = (const int*)d_in[3];    // [V]
    float* out = (float*)d_out;                 // [B,V]

    char* ws = (char*)d_ws;
    int*   cnt    = (int*)(ws + WS_CNT);
    int*   qs     = (int*)(ws + WS_QS);
    int*   cursor = (int*)(ws + WS_CURS);
    int*   sorted = (int*)(ws + WS_SORTED);
    int*   posOf  = (int*)(ws + WS_POSOF);
    float* res    = (float*)(ws + WS_RES);

    hipMemsetAsync(cnt, 0, 256 * sizeof(int), stream);
    count_k<<<80, 256, 0, stream>>>(pid, cnt);
    scan_k<<<1, 256, 0, stream>>>(cnt, qs, cursor);
    scatter_k<<<80, 256, 0, stream>>>(pid, cursor, sorted, posOf);

    main_k<<<4 * QQ, 256, 0, stream>>>(OT, W, sorted, qs, cnt, res);

    combine_k<<<dim3((VV + 255) / 256, BB), 256, 0, stream>>>(res, posOf, bias, out);
}